// Round 9
// baseline (1175.269 us; speedup 1.0000x reference)
//
#include <hip/hip_runtime.h>
#include <hip/hip_bf16.h>

typedef _Float16 h2v __attribute__((ext_vector_type(2)));

#define B_SZ 64
#define T_SZ 512
#define E_SZ 256
#define H_SZ 256
#define C_SZ 768   // 3*H

__device__ __forceinline__ float dot2f(h2v a, h2v b, float c) {
#if __has_builtin(__builtin_amdgcn_fdot2)
  return __builtin_amdgcn_fdot2(a, b, c, false);
#else
  return c + (float)a[0] * (float)b[0] + (float)a[1] * (float)b[1];
#endif
}

__device__ __forceinline__ float rcp_fast(float x) {
  return __builtin_amdgcn_rcpf(x);
}

// DPP quad_perm add with lane^1 partner (VALU pipe)
__device__ __forceinline__ float dpp_add_x1(float v) {
  int i = __builtin_bit_cast(int, v);
  int s = __builtin_amdgcn_update_dpp(i, i, 0xB1, 0xF, 0xF, true); // quad_perm [1,0,3,2]
  return v + __builtin_bit_cast(float, s);
}

// ---------------------------------------------------------------------------
// Kernel 1: xp[dir][row][c] = (emb[x[row]] @ kernel_dir)[c] + bias_dir[0][c]
// UNCHANGED (measured ~441us, ~75% of its fdot2 VALU floor; MFMA rewrite is
// the next isolated change).
// ---------------------------------------------------------------------------
__global__ __launch_bounds__(256) void xp_gemm_kernel(
    const int* __restrict__ x,
    const float* __restrict__ emb,
    const float* __restrict__ kf, const float* __restrict__ bf,
    const float* __restrict__ kb, const float* __restrict__ bb,
    _Float16* __restrict__ xp)
{
  const int ct  = blockIdx.x;   // 16 col tiles of 48
  const int rt  = blockIdx.y;   // 512 row tiles of 64
  const int dir = blockIdx.z;
  const float* Kp = dir ? kb : kf;
  const float* Bp = dir ? bb : bf;
  const int c0 = ct * 48;
  const int r0 = rt * 64;
  const int tid = threadIdx.x;

  __shared__ __align__(16) _Float16 As[64][264];
  __shared__ __align__(16) _Float16 Bs[48][264];

  for (int r = 0; r < 64; ++r) {
    int xi = x[r0 + r];
    As[r][tid] = (_Float16)emb[(size_t)xi * E_SZ + tid];
  }
  for (int i = tid; i < 48 * 256; i += 256) {
    int k = i / 48;
    int c = i - k * 48;
    Bs[c][k] = (_Float16)Kp[k * C_SZ + c0 + c];
  }
  __syncthreads();

  const int tr = tid >> 4;
  const int tc = tid & 15;
  float acc[4][3];
  #pragma unroll
  for (int i = 0; i < 4; ++i)
    #pragma unroll
    for (int j = 0; j < 3; ++j) acc[i][j] = 0.f;

  #pragma unroll
  for (int m = 0; m < 32; ++m) {
    float4 a4[4], b4[3];
    #pragma unroll
    for (int i = 0; i < 4; ++i) a4[i] = *(const float4*)&As[tr * 4 + i][m * 8];
    #pragma unroll
    for (int j = 0; j < 3; ++j) b4[j] = *(const float4*)&Bs[tc + 16 * j][m * 8];
    #pragma unroll
    for (int i = 0; i < 4; ++i) {
      const h2v* ah = (const h2v*)&a4[i];
      #pragma unroll
      for (int j = 0; j < 3; ++j) {
        const h2v* bh = (const h2v*)&b4[j];
        #pragma unroll
        for (int p = 0; p < 4; ++p) acc[i][j] = dot2f(ah[p], bh[p], acc[i][j]);
      }
    }
  }

  #pragma unroll
  for (int j = 0; j < 3; ++j) {
    int c = c0 + tc + 16 * j;
    float bias = Bp[c];
    #pragma unroll
    for (int i = 0; i < 4; ++i) {
      int r = r0 + tr * 4 + i;
      xp[((size_t)dir * (B_SZ * T_SZ) + r) * C_SZ + c] = (_Float16)(acc[i][j] + bias);
    }
  }
}

// ---------------------------------------------------------------------------
// Kernel 2: GRU scan — 512 threads, pair-split K, 3 outputs per thread.
// Round-8 post-mortem: 768 thr = 3 waves/SIMD = 170-reg unified budget, but
// live set needs ~230 => allocator parked col[] in AGPR (+scratch), costing a
// v_accvgpr_read per dot2. Geometry fix: 512 thr = 2 waves/SIMD = 256-reg
// budget. Pair p=t>>1 owns outputs {3p,3p+1,3p+2}; thread t does K-half
// [128*(t&1), +128). col = 3x64 h2v = 192 VGPRs + ~40 misc <= 256.
// Pair-reduce = 1 DPP lane^1 add. h slices at 136-f16 stride: even/odd lanes
// read disjoint banks.
// ---------------------------------------------------------------------------
__global__ __launch_bounds__(512) __attribute__((amdgpu_waves_per_eu(2, 2)))
void gru_scan_kernel(
    const float* __restrict__ hidden,
    const float* __restrict__ rkf, const float* __restrict__ bf,
    const float* __restrict__ rkb, const float* __restrict__ bb,
    const _Float16* __restrict__ xp,
    float* __restrict__ out)
{
  const int b    = blockIdx.x;
  const int dir  = blockIdx.y;
  const int tid  = threadIdx.x;   // 0..511
  const int pair = tid >> 1;      // 0..255 -> outputs 3p,3p+1,3p+2
  const int half = tid & 1;       // K-half owner
  const float* RK = dir ? rkb : rkf;
  const float* BS = dir ? bb : bf;

  __shared__ __align__(16) _Float16 hbuf[2 * 136]; // slice s at 136*s (272B stride)
  __shared__ __align__(16) float hp[C_SZ];

  // col[o][m] = RK[128*half + 2m (+1)][3*pair + o] as f16 pair.
  // volatile: loads execute exactly once; asm: origin opaque to allocator.
  h2v col[3][64];
  const int cbase = 3 * pair;
  #pragma unroll
  for (int o = 0; o < 3; ++o) {
    #pragma unroll
    for (int m = 0; m < 64; ++m) {
      int k = 128 * half + 2 * m;
      volatile const float* rk0 = RK + (size_t)k * C_SZ + cbase + o;
      volatile const float* rk1 = RK + (size_t)(k + 1) * C_SZ + cbase + o;
      h2v c2;
      c2[0] = (_Float16)(*rk0);
      c2[1] = (_Float16)(*rk1);
      col[o][m] = c2;
    }
  }
  #pragma unroll
  for (int o = 0; o < 3; ++o)
    #pragma unroll
    for (int m = 0; m < 64; ++m)
      asm volatile("" : "+v"(col[o][m]));

  // recurrent bias for this pair's 3 outputs (row 1 of bias)
  float rb0 = BS[C_SZ + cbase + 0];
  float rb1 = BS[C_SZ + cbase + 1];
  float rb2 = BS[C_SZ + cbase + 2];

  float hreg = 0.f;
  if (tid < H_SZ) {
    hreg = hidden[b * H_SZ + tid];
    hbuf[136 * (tid >> 7) + (tid & 127)] = (_Float16)hreg;
  }

  const size_t xbase = ((size_t)dir * (B_SZ * T_SZ) + (size_t)b * T_SZ) * C_SZ;
  float xz_c = 0.f, xr_c = 0.f, xh_c = 0.f;
  if (tid < H_SZ) {
    int t0 = dir ? (T_SZ - 1) : 0;
    const _Float16* xr0 = xp + xbase + (size_t)t0 * C_SZ;
    xz_c = (float)xr0[tid];
    xr_c = (float)xr0[tid + H_SZ];
    xh_c = (float)xr0[tid + 2 * H_SZ];
  }
  __syncthreads();

  for (int s = 0; s < T_SZ; ++s) {
    // prefetch next step's xp row (hides under the matvec)
    float xz_n = 0.f, xr_n = 0.f, xh_n = 0.f;
    if (tid < H_SZ) {
      int sn = (s + 1 < T_SZ) ? (s + 1) : s;
      int tn = dir ? (T_SZ - 1 - sn) : sn;
      const _Float16* xrn = xp + xbase + (size_t)tn * C_SZ;
      xz_n = (float)xrn[tid];
      xr_n = (float)xrn[tid + H_SZ];
      xh_n = (float)xrn[tid + 2 * H_SZ];
    }

    // partial dots over own K-half for the pair's 3 outputs.
    // Chunked 4x(4 b128 + 48 dot2) to bound live h registers.
    float acc0 = 0.f, acc1 = 0.f, acc2 = 0.f;
    const float4* hsl = (const float4*)(hbuf + 136 * half);
    #pragma unroll
    for (int c4 = 0; c4 < 4; ++c4) {
      float4 q0 = hsl[4 * c4 + 0];
      float4 q1 = hsl[4 * c4 + 1];
      float4 q2 = hsl[4 * c4 + 2];
      float4 q3 = hsl[4 * c4 + 3];
      const h2v* h0 = (const h2v*)&q0;
      const h2v* h1 = (const h2v*)&q1;
      const h2v* h2 = (const h2v*)&q2;
      const h2v* h3 = (const h2v*)&q3;
      int mb = 16 * c4;
      #pragma unroll
      for (int p = 0; p < 4; ++p) {
        acc0 = dot2f(h0[p], col[0][mb + p], acc0);
        acc1 = dot2f(h0[p], col[1][mb + p], acc1);
        acc2 = dot2f(h0[p], col[2][mb + p], acc2);
        acc0 = dot2f(h1[p], col[0][mb + 4 + p], acc0);
        acc1 = dot2f(h1[p], col[1][mb + 4 + p], acc1);
        acc2 = dot2f(h1[p], col[2][mb + 4 + p], acc2);
        acc0 = dot2f(h2[p], col[0][mb + 8 + p], acc0);
        acc1 = dot2f(h2[p], col[1][mb + 8 + p], acc1);
        acc2 = dot2f(h2[p], col[2][mb + 8 + p], acc2);
        acc0 = dot2f(h3[p], col[0][mb + 12 + p], acc0);
        acc1 = dot2f(h3[p], col[1][mb + 12 + p], acc1);
        acc2 = dot2f(h3[p], col[2][mb + 12 + p], acc2);
      }
    }
    // pair reduce (lane^1, VALU): both lanes get full sums
    acc0 = dpp_add_x1(acc0);
    acc1 = dpp_add_x1(acc1);
    acc2 = dpp_add_x1(acc2);
    // even lane writes outputs 0,1; odd lane writes output 2
    if (half == 0) {
      hp[cbase + 0] = acc0 + rb0;
      hp[cbase + 1] = acc1 + rb1;
    } else {
      hp[cbase + 2] = acc2 + rb2;
    }
    __syncthreads();

    if (tid < H_SZ) {
      float z  = rcp_fast(1.f + __expf(-(xz_c + hp[tid])));
      float r  = rcp_fast(1.f + __expf(-(xr_c + hp[tid + H_SZ])));
      float pre = xh_c + r * hp[tid + 2 * H_SZ];
      float e2 = __expf(2.f * pre);
      float hc = 1.f - 2.f * rcp_fast(e2 + 1.f);   // tanh(pre)
      hreg = z * hreg + (1.f - z) * hc;
      int t = dir ? (T_SZ - 1 - s) : s;
      out[((size_t)b * T_SZ + t) * (2 * H_SZ) + dir * H_SZ + tid] = hreg;
      hbuf[136 * (tid >> 7) + (tid & 127)] = (_Float16)hreg;
    }
    __syncthreads();

    xz_c = xz_n; xr_c = xr_n; xh_c = xh_n;
  }

  if (tid < H_SZ) {
    out[(size_t)(B_SZ * T_SZ) * (2 * H_SZ) + dir * (B_SZ * H_SZ) + b * H_SZ + tid] = hreg;
  }
}

// ---------------------------------------------------------------------------
extern "C" void kernel_launch(void* const* d_in, const int* in_sizes, int n_in,
                              void* d_out, int out_size, void* d_ws, size_t ws_size,
                              hipStream_t stream) {
  const int*   x    = (const int*)d_in[0];
  const float* hid  = (const float*)d_in[1];
  const float* emb  = (const float*)d_in[2];
  const float* kf   = (const float*)d_in[3];
  const float* rkf  = (const float*)d_in[4];
  const float* bf   = (const float*)d_in[5];
  const float* kb   = (const float*)d_in[6];
  const float* rkb  = (const float*)d_in[7];
  const float* bb   = (const float*)d_in[8];
  float* out = (float*)d_out;

  _Float16* xp = (_Float16*)d_ws;  // [2][B*T][768] f16 = 100,663,296 bytes

  dim3 g1(16, 512, 2);
  xp_gemm_kernel<<<g1, 256, 0, stream>>>(x, emb, kf, bf, kb, bb, xp);

  dim3 g2(B_SZ, 2);
  gru_scan_kernel<<<g2, 512, 0, stream>>>(hid, rkf, bf, rkb, bb, xp, out);
}